// Round 1
// 10374.492 us; speedup vs baseline: 1.1037x; 1.1037x over previous
//
#include <hip/hip_runtime.h>
#include <hip/hip_bf16.h>

#define TT 256
#define BB 64
#define VV 10000
#define DD 256
#define HH 1024
#define KTOT 1280   // DD + HH
#define NBLK 64     // LSTM blocks; each owns 16 h-columns

typedef short bf16x8 __attribute__((ext_vector_type(8)));
typedef float f32x4 __attribute__((ext_vector_type(4)));

typedef unsigned int uint_g __attribute__((address_space(1)));
typedef unsigned int uint_l __attribute__((address_space(3)));

__device__ __forceinline__ void gl_lds16(const void* g, void* l) {
  __builtin_amdgcn_global_load_lds((const uint_g*)g, (uint_l*)l, 16, 0, 0);
}

__device__ __forceinline__ float sigf(float x) { return 1.0f / (1.0f + __expf(-x)); }

// Custom grid barrier state (monotonic counter; zeroed before each launch).
__device__ int g_bar;

__global__ void ptb_zero_bar() {
  if (threadIdx.x == 0) g_bar = 0;
}

// ---------------- prep kernels ----------------

// W_big layout: [blk 0..63][r 0..63][k 0..1279] bf16, r = wave*16 + nl,
// nl -> (gate g = nl>>2, col c = nl&3); global gate row = g*1024 + blk*16 + wave*4 + c
// k<256 -> W_ih row, else W_hh row.
__global__ void ptb_prep_wbig(const float* __restrict__ Wih, const float* __restrict__ Whh,
                              __hip_bfloat16* __restrict__ wbig) {
  const int total = NBLK * 64 * KTOT;
  for (int idx = blockIdx.x * blockDim.x + threadIdx.x; idx < total;
       idx += gridDim.x * blockDim.x) {
    const int k = idx % KTOT;
    const int rr = idx / KTOT;
    const int blk = rr >> 6;
    const int r = rr & 63;
    const int wv = r >> 4;
    const int nl = r & 15;
    const int g = nl >> 2, c = nl & 3;
    const int grow = g * HH + blk * 16 + wv * 4 + c;
    const float v = (k < DD) ? Wih[(size_t)grow * DD + k]
                             : Whh[(size_t)grow * HH + (k - DD)];
    wbig[idx] = __float2bfloat16(v);
  }
}

__global__ void ptb_f32_to_bf16(const float* __restrict__ src,
                                __hip_bfloat16* __restrict__ dst, int n) {
  for (int i = blockIdx.x * blockDim.x + threadIdx.x; i < n;
       i += gridDim.x * blockDim.x)
    dst[i] = __float2bfloat16(src[i]);
}

// ---------------- persistent LSTM kernel (cooperative) ----------------
// 64 blocks x 256 threads. Wave wv of block blk owns h-cols blk*16 + wv*4 .. +3
// (16 gate rows: nl -> gate nl>>2, col nl&3). Direct-global MFMA operand loads.
// Per-step sync: custom monotonic-counter barrier (grid.sync() measured ~30+us/step;
// this is ~1-2us: one agent-scope atomicAdd per block + tight relaxed poll).
__global__ __launch_bounds__(256)
void ptb_lstm(const int* __restrict__ tokens, const float* __restrict__ c0,
              const float* __restrict__ bias, const __hip_bfloat16* __restrict__ wbig,
              const __hip_bfloat16* __restrict__ embb, __hip_bfloat16* __restrict__ hs,
              float* __restrict__ out_hT, float* __restrict__ out_cT) {
  const int tid = threadIdx.x;
  const int blk = blockIdx.x;
  const int lane = tid & 63;
  const int wv = tid >> 6;
  const int quad = lane >> 4;
  const int nl = lane & 15;
  const int qbase = lane & 48;
  const int cidx = nl & 3;   // epilogue col-within-wave
  const int ridx = nl >> 2;  // epilogue row-within-quad

  // per-lane W row pointer (B operand): row = blk*64 + wv*16 + nl, k offset quad*8
  const __hip_bfloat16* wrow =
      wbig + (size_t)(blk * 64 + wv * 16 + nl) * KTOT + quad * 8;

  const int colg = blk * 16 + wv * 4 + cidx;  // global h-column this lane updates
  const float bi = bias[colg];
  const float bf_ = bias[HH + colg];
  const float bg = bias[2 * HH + colg];
  const float bo = bias[3 * HH + colg];

  // c-state: lane owns (m = mt*16 + quad*4 + ridx, colg) for mt = 0..3
  float creg[4];
#pragma unroll
  for (int mt = 0; mt < 4; ++mt)
    creg[mt] = c0[(size_t)(mt * 16 + quad * 4 + ridx) * HH + colg];

  for (int t = 0; t < TT; ++t) {
    const __hip_bfloat16* hsp = hs + (size_t)t * (BB * HH);

    // per-lane A-operand row pointers (m = mt*16 + nl)
    const __hip_bfloat16* xp[4];
    const __hip_bfloat16* hp[4];
#pragma unroll
    for (int mt = 0; mt < 4; ++mt) {
      const int m = mt * 16 + nl;
      const int tok = tokens[t * BB + m];
      xp[mt] = embb + (size_t)tok * DD + quad * 8;
      hp[mt] = hsp + (size_t)m * HH + quad * 8;
    }

    f32x4 acc[4];
#pragma unroll
    for (int mt = 0; mt < 4; ++mt) {
      acc[mt][0] = 0.f; acc[mt][1] = 0.f; acc[mt][2] = 0.f; acc[mt][3] = 0.f;
    }

    // x part: K = 0..255
#pragma unroll
    for (int s = 0; s < 8; ++s) {
      const bf16x8 wf = *(const bf16x8*)(wrow + s * 32);
#pragma unroll
      for (int mt = 0; mt < 4; ++mt) {
        const bf16x8 af = *(const bf16x8*)(xp[mt] + s * 32);
        acc[mt] = __builtin_amdgcn_mfma_f32_16x16x32_bf16(af, wf, acc[mt], 0, 0, 0);
      }
    }
    // h part: K = 256..1279
#pragma unroll 8
    for (int s = 0; s < 32; ++s) {
      const bf16x8 wf = *(const bf16x8*)(wrow + 256 + s * 32);
#pragma unroll
      for (int mt = 0; mt < 4; ++mt) {
        const bf16x8 af = *(const bf16x8*)(hp[mt] + s * 32);
        acc[mt] = __builtin_amdgcn_mfma_f32_16x16x32_bf16(af, wf, acc[mt], 0, 0, 0);
      }
    }

    // epilogue: gather i,f,g,o for this lane's (m, colg) via intra-wave shuffles
    __hip_bfloat16* hout = hs + (size_t)(t + 1) * (BB * HH);
#pragma unroll
    for (int mt = 0; mt < 4; ++mt) {
      float iv = 0.f, fv = 0.f, gv = 0.f, ov = 0.f;
#pragma unroll
      for (int r = 0; r < 4; ++r) {
        const float s0 = __shfl(acc[mt][r], qbase + cidx, 64);        // gate i lane
        const float s1 = __shfl(acc[mt][r], qbase + 4 + cidx, 64);    // gate f lane
        const float s2 = __shfl(acc[mt][r], qbase + 8 + cidx, 64);    // gate g lane
        const float s3 = __shfl(acc[mt][r], qbase + 12 + cidx, 64);   // gate o lane
        if (ridx == r) { iv = s0; fv = s1; gv = s2; ov = s3; }
      }
      const float ig = sigf(iv + bi);
      const float fg = sigf(fv + bf_);
      const float gg = tanhf(gv + bg);
      const float og = sigf(ov + bo);
      const float cn = fg * creg[mt] + ig * gg;
      creg[mt] = cn;
      const float hn = og * tanhf(cn);
      const int m = mt * 16 + quad * 4 + ridx;
      hout[(size_t)m * HH + colg] = __float2bfloat16(hn);
      if (t == TT - 1) {
        out_hT[(size_t)m * HH + colg] = hn;
        out_cT[(size_t)m * HH + colg] = cn;
      }
    }

    // ---- custom grid barrier (release h[t+1]; acquire peers' slices) ----
    if (t != TT - 1) {
      __threadfence();      // drain stores + L2 writeback (cross-XCD release)
      __syncthreads();      // all waves of this block have fenced
      if (tid == 0) {
        __hip_atomic_fetch_add(&g_bar, 1, __ATOMIC_RELEASE,
                               __HIP_MEMORY_SCOPE_AGENT);
        const int target = NBLK * (t + 1);
        while (__hip_atomic_load(&g_bar, __ATOMIC_RELAXED,
                                 __HIP_MEMORY_SCOPE_AGENT) < target)
          __builtin_amdgcn_s_sleep(1);
      }
      __syncthreads();
      __threadfence();      // invalidate L1/L2 before reading peers' h (acquire)
    }
  }
}

// ---------------- logits GEMM ----------------
// C[16384 x 10000] = A[16384 x 1024](bf16, hs rows 1..256) @ B^T (W_out bf16) + b_out
// 128x128 tile, BK=64, global_load_lds staging into [kc][row] interleaved layout.
__global__ __launch_bounds__(256, 2)
void ptb_logits(const __hip_bfloat16* __restrict__ A, const __hip_bfloat16* __restrict__ Bw,
                const float* __restrict__ bout, float* __restrict__ out) {
  __shared__ char ldsA[16384];  // [kc 0..7][m 0..127] x 16B
  __shared__ char ldsB[16384];  // [kc 0..7][n 0..127] x 16B

  const int tid = threadIdx.x;
  const int lane = tid & 63;
  const int wv = tid >> 6;
  const int wm = wv & 1;        // which 64-row half of M-tile
  const int wn = wv >> 1;       // which 64-col half of N-tile
  const int quad = lane >> 4;
  const int nl = lane & 15;

  const int m0 = blockIdx.y * 128;
  const int n0 = blockIdx.x * 128;

  const int srow = tid & 127;   // staging row this thread fills
  int browg = n0 + srow;
  if (browg >= VV) browg = 0;   // clamp OOB cols to a safe address; masked at store
  const __hip_bfloat16* arow = A + (size_t)(m0 + srow) * HH;
  const __hip_bfloat16* brow = Bw + (size_t)browg * HH;

  f32x4 acc[4][4];
#pragma unroll
  for (int mt = 0; mt < 4; ++mt)
#pragma unroll
    for (int nt = 0; nt < 4; ++nt) {
      acc[mt][nt][0] = 0.f; acc[mt][nt][1] = 0.f;
      acc[mt][nt][2] = 0.f; acc[mt][nt][3] = 0.f;
    }

  for (int k0 = 0; k0 < HH; k0 += 64) {
#pragma unroll
    for (int it = 0; it < 4; ++it) {
      const int seg = it * 256 + tid;
      const int kc = seg >> 7;  // 0..7
      gl_lds16(arow + k0 + kc * 8, ldsA + seg * 16);
      gl_lds16(brow + k0 + kc * 8, ldsB + seg * 16);
    }
    __syncthreads();
#pragma unroll
    for (int kk = 0; kk < 2; ++kk) {
      bf16x8 af[4], bf[4];
#pragma unroll
      for (int mt = 0; mt < 4; ++mt)
        af[mt] = *(const bf16x8*)(ldsA + ((kk * 4 + quad) * 128 + wm * 64 + mt * 16 + nl) * 16);
#pragma unroll
      for (int nt = 0; nt < 4; ++nt)
        bf[nt] = *(const bf16x8*)(ldsB + ((kk * 4 + quad) * 128 + wn * 64 + nt * 16 + nl) * 16);
#pragma unroll
      for (int mt = 0; mt < 4; ++mt)
#pragma unroll
        for (int nt = 0; nt < 4; ++nt)
          acc[mt][nt] = __builtin_amdgcn_mfma_f32_16x16x32_bf16(af[mt], bf[nt], acc[mt][nt], 0, 0, 0);
    }
    __syncthreads();
  }

#pragma unroll
  for (int nt = 0; nt < 4; ++nt) {
    const int col = n0 + wn * 64 + nt * 16 + nl;
    if (col < VV) {
      const float bb = bout[col];
#pragma unroll
      for (int mt = 0; mt < 4; ++mt) {
        const int mr = m0 + wm * 64 + mt * 16 + quad * 4;
#pragma unroll
        for (int r = 0; r < 4; ++r)
          out[(size_t)(mr + r) * VV + col] = acc[mt][nt][r] + bb;
      }
    }
  }
}

// ---------------- launch ----------------

extern "C" void kernel_launch(void* const* d_in, const int* in_sizes, int n_in,
                              void* d_out, int out_size, void* d_ws, size_t ws_size,
                              hipStream_t stream) {
  (void)in_sizes; (void)n_in; (void)out_size; (void)ws_size;

  const int* tokens = (const int*)d_in[0];
  const float* h0 = (const float*)d_in[1];
  const float* c0 = (const float*)d_in[2];
  const float* emb = (const float*)d_in[3];
  const float* Wih = (const float*)d_in[4];
  const float* Whh = (const float*)d_in[5];
  const float* bias = (const float*)d_in[6];
  const float* Wout = (const float*)d_in[7];
  const float* bout = (const float*)d_in[8];
  float* out = (float*)d_out;

  // ws layout (bytes): W_big 10,485,760 | emb_bf 5,120,000 | W_out_bf 20,480,000 |
  //                    hs (257 x 64 x 1024 bf16) 33,685,504  => ~66.5 MB total
  char* ws = (char*)d_ws;
  __hip_bfloat16* wbig  = (__hip_bfloat16*)(ws);
  __hip_bfloat16* embb  = (__hip_bfloat16*)(ws + 10485760);
  __hip_bfloat16* woutb = (__hip_bfloat16*)(ws + 15605760);
  __hip_bfloat16* hsbuf = (__hip_bfloat16*)(ws + 36085760);

  ptb_zero_bar<<<1, 64, 0, stream>>>();
  ptb_prep_wbig<<<4096, 256, 0, stream>>>(Wih, Whh, wbig);
  ptb_f32_to_bf16<<<2048, 256, 0, stream>>>(emb, embb, VV * DD);
  ptb_f32_to_bf16<<<4096, 256, 0, stream>>>(Wout, woutb, VV * HH);
  ptb_f32_to_bf16<<<64, 256, 0, stream>>>(h0, hsbuf, BB * HH);  // hs[0] = h0

  float* out_hT = out + (size_t)TT * BB * VV;
  float* out_cT = out_hT + (size_t)BB * HH;

  void* args[] = {(void*)&tokens, (void*)&c0, (void*)&bias, (void*)&wbig,
                  (void*)&embb, (void*)&hsbuf, (void*)&out_hT, (void*)&out_cT};
  hipLaunchCooperativeKernel((const void*)ptb_lstm, dim3(NBLK), dim3(256),
                             args, 0, stream);

  ptb_logits<<<dim3(79, 128), 256, 0, stream>>>(hsbuf + BB * HH, woutb, bout, out);
}